// Round 2
// baseline (13157.718 us; speedup 1.0000x reference)
//
#include <hip/hip_runtime.h>

// Actor: state[B,10] -> 4x BiGRU(H=10,T=5,in=1) -> concat[40] -> l1(40->20,selu) -> l2(20->2) -> clip
// One thread per batch row. Weights staged in LDS (wave-uniform broadcast reads).
// R2: register-pressure-focused restructure (R1 spilled: VGPR=256, 1.7GB scratch writes).

#define NH 10

__device__ __forceinline__ float fexp(float x) { return __expf(x); }                // v_exp_f32 path
__device__ __forceinline__ float frcp(float x) { return __builtin_amdgcn_rcpf(x); } // v_rcp_f32
__device__ __forceinline__ float fsigmoid(float x) { return frcp(1.0f + fexp(-x)); }
__device__ __forceinline__ float ftanh(float x) {
    // tanh(x) = 1 - 2/(exp(2x)+1); safe at both extremes (e->0 => -1, e->inf => 1)
    float e = fexp(2.0f * x);
    return 1.0f - 2.0f * frcp(e + 1.0f);
}

__global__ __launch_bounds__(256, 4) void actor_kernel(
    const float* __restrict__ state,
    const float* __restrict__ wih0, const float* __restrict__ whh0,
    const float* __restrict__ bih0, const float* __restrict__ bhh0,
    const float* __restrict__ wih1, const float* __restrict__ whh1,
    const float* __restrict__ bih1, const float* __restrict__ bhh1,
    const float* __restrict__ wih2, const float* __restrict__ whh2,
    const float* __restrict__ bih2, const float* __restrict__ bhh2,
    const float* __restrict__ wih3, const float* __restrict__ whh3,
    const float* __restrict__ bih3, const float* __restrict__ bhh3,
    const float* __restrict__ l1w, const float* __restrict__ l1b,
    const float* __restrict__ l2w, const float* __restrict__ l2b,
    float* __restrict__ out, int Btot)
{
    // LDS staging (all later reads are wave-uniform -> broadcast, no bank conflicts)
    __shared__ __align__(16) float s_whh[4][30][12];  // rows padded 10->12 floats
    __shared__ float s_wih[4][30];
    __shared__ float s_bih[4][30];
    __shared__ float s_bhh[4][30];
    __shared__ __align__(16) float s_l1w[20][40];
    __shared__ float s_l1b[20];
    __shared__ float s_l2w[2][20];
    __shared__ float s_l2b[2];

    const int tid = threadIdx.x;

#define LOAD_DIR(d, wih, whh, bih, bhh)                                         \
    for (int i = tid; i < 300; i += 256) s_whh[d][i / 10][i % 10] = whh[i];     \
    for (int i = tid; i < 30; i += 256) {                                       \
        s_wih[d][i] = wih[i]; s_bih[d][i] = bih[i]; s_bhh[d][i] = bhh[i];       \
    }

    LOAD_DIR(0, wih0, whh0, bih0, bhh0)
    LOAD_DIR(1, wih1, whh1, bih1, bhh1)
    LOAD_DIR(2, wih2, whh2, bih2, bhh2)
    LOAD_DIR(3, wih3, whh3, bih3, bhh3)
#undef LOAD_DIR
    for (int i = tid; i < 800; i += 256) s_l1w[i / 40][i % 40] = l1w[i];
    for (int i = tid; i < 20; i += 256) s_l1b[i] = l1b[i];
    for (int i = tid; i < 40; i += 256) s_l2w[i / 20][i % 20] = l2w[i];
    for (int i = tid; i < 2; i += 256) s_l2b[i] = l2b[i];
    __syncthreads();

    const int b = blockIdx.x * 256 + tid;
    if (b >= Btot) return;

    // This row's 10 state values (two halves, statically indexed)
    float xf[5], xs[5];
    {
        const float* srow = state + (size_t)b * 10;
#pragma unroll
        for (int i = 0; i < 5; ++i) xf[i] = srow[i];
#pragma unroll
        for (int i = 0; i < 5; ++i) xs[i] = srow[5 + i];
    }

    // l1 accumulator (selu at the end); avoids materializing feats[40]
    float a1[20];
#pragma unroll
    for (int o = 0; o < 20; ++o) a1[o] = s_l1b[o];

    // 4 directions: d=0: grp1 fwd, d=1: grp1 bwd, d=2: grp2 fwd, d=3: grp2 bwd
#pragma unroll 1
    for (int d = 0; d < 4; ++d) {
        const int rev = d & 1;
        const int grp2 = (d >= 2);

        // wave-uniform LDS base pointers for this direction
        const float* whh_d = &s_whh[d][0][0];   // row stride 12
        const float* wih_d = &s_wih[d][0];
        const float* bih_d = &s_bih[d][0];
        const float* bhh_d = &s_bhh[d][0];
        const float* l1w_col = &s_l1w[0][0] + d * 10;  // row stride 40

        // x queue for this direction: xq[0] consumed first, then shift.
        float xq[5];
#pragma unroll
        for (int i = 0; i < 5; ++i) {
            float a = grp2 ? xs[i] : xf[i];
            float b2 = grp2 ? xs[4 - i] : xf[4 - i];
            xq[i] = rev ? b2 : a;
        }

        float h[NH];
#pragma unroll
        for (int j = 0; j < NH; ++j) h[j] = 0.0f;

#pragma unroll 1
        for (int tt = 0; tt < 5; ++tt) {
            const float xt = xq[0];
#pragma unroll
            for (int i = 0; i < 4; ++i) xq[i] = xq[i + 1];

            float hnew[NH];
#pragma unroll
            for (int j = 0; j < NH; ++j) {
                // three dot products over old h (minimal live temps)
                float ar = bhh_d[j];
                float az = bhh_d[j + 10];
                float an = bhh_d[j + 20];
#pragma unroll
                for (int k = 0; k < NH; ++k) {
                    ar = fmaf(whh_d[j * 12 + k], h[k], ar);
                    az = fmaf(whh_d[(j + 10) * 12 + k], h[k], az);
                    an = fmaf(whh_d[(j + 20) * 12 + k], h[k], an);
                }
                float r = fsigmoid(fmaf(xt, wih_d[j], bih_d[j]) + ar);
                float z = fsigmoid(fmaf(xt, wih_d[j + 10], bih_d[j + 10]) + az);
                float n = ftanh(fmaf(xt, wih_d[j + 20], bih_d[j + 20]) + r * an);
                hnew[j] = n + z * (h[j] - n);   // (1-z)*n + z*h
            }
#pragma unroll
            for (int j = 0; j < NH; ++j) h[j] = hnew[j];
        }

        // a1[o] += sum_j h[j] * l1w[o][d*10+j]
#pragma unroll
        for (int o = 0; o < 20; ++o) {
            float s = a1[o];
#pragma unroll
            for (int j = 0; j < NH; ++j) s = fmaf(h[j], l1w_col[o * 40 + j], s);
            a1[o] = s;
        }
    }

    // SELU
    const float SC = 1.0507009873554805f;
    const float AL = 1.6732632423543772f;
#pragma unroll
    for (int o = 0; o < 20; ++o) {
        float s = a1[o];
        a1[o] = (s > 0.0f) ? SC * s : SC * AL * (fexp(s) - 1.0f);
    }

    // l2 (20 -> 2) + clip
    float o0 = s_l2b[0], o1 = s_l2b[1];
#pragma unroll
    for (int i = 0; i < 20; ++i) {
        o0 = fmaf(a1[i], s_l2w[0][i], o0);
        o1 = fmaf(a1[i], s_l2w[1][i], o1);
    }
    o0 = fminf(1.0f, fmaxf(-1.0f, o0));
    o1 = fminf(1.0f, fmaxf(-1.0f, o1));

    reinterpret_cast<float2*>(out)[b] = make_float2(o0, o1);
}

extern "C" void kernel_launch(void* const* d_in, const int* in_sizes, int n_in,
                              void* d_out, int out_size, void* d_ws, size_t ws_size,
                              hipStream_t stream) {
    const float* state = (const float*)d_in[0];
    const int B = in_sizes[0] / 10;
    const int grid = (B + 255) / 256;

    actor_kernel<<<grid, 256, 0, stream>>>(
        state,
        (const float*)d_in[1],  (const float*)d_in[2],  (const float*)d_in[3],  (const float*)d_in[4],
        (const float*)d_in[5],  (const float*)d_in[6],  (const float*)d_in[7],  (const float*)d_in[8],
        (const float*)d_in[9],  (const float*)d_in[10], (const float*)d_in[11], (const float*)d_in[12],
        (const float*)d_in[13], (const float*)d_in[14], (const float*)d_in[15], (const float*)d_in[16],
        (const float*)d_in[17], (const float*)d_in[18], (const float*)d_in[19], (const float*)d_in[20],
        (float*)d_out, B);
}

// Round 3
// 658.219 us; speedup vs baseline: 19.9899x; 19.9899x over previous
//
#include <hip/hip_runtime.h>

// Actor: state[B,10] -> 4x GRU dir(H=10,T=5,in=1) -> concat[40] -> l1(40->20,selu) -> l2(20->2) -> clip
// R3: 4 lanes per row (one GRU direction each) to keep live set < 64 VGPR (R2 spilled
// catastrophically at VGPR=64 budget). Biases folded into padded weight rows; all weight
// reads are 4-way-broadcast ds_read_b128 (conflict-free). Quad shfl_xor reduce for l1.

#define NH 10

__device__ __forceinline__ float fexp(float x) { return __expf(x); }
__device__ __forceinline__ float frcp(float x) { return __builtin_amdgcn_rcpf(x); }
__device__ __forceinline__ float fsigmoid(float x) { return frcp(1.0f + fexp(-x)); }
__device__ __forceinline__ float ftanh(float x) {
    float e = fexp(2.0f * x);
    return 1.0f - 2.0f * frcp(e + 1.0f);
}

// acc += dot(row[0..9], h[0..9]) where row is 3 float4 chunks (c2.z/.w are bias/wih)
#define DOT10(acc, c0, c1, c2)                                   \
    acc = fmaf((c0).x, h[0], acc); acc = fmaf((c0).y, h[1], acc);\
    acc = fmaf((c0).z, h[2], acc); acc = fmaf((c0).w, h[3], acc);\
    acc = fmaf((c1).x, h[4], acc); acc = fmaf((c1).y, h[5], acc);\
    acc = fmaf((c1).z, h[6], acc); acc = fmaf((c1).w, h[7], acc);\
    acc = fmaf((c2).x, h[8], acc); acc = fmaf((c2).y, h[9], acc);

__global__ __launch_bounds__(256) void actor_kernel(
    const float* __restrict__ state,
    const float* __restrict__ wih0, const float* __restrict__ whh0,
    const float* __restrict__ bih0, const float* __restrict__ bhh0,
    const float* __restrict__ wih1, const float* __restrict__ whh1,
    const float* __restrict__ bih1, const float* __restrict__ bhh1,
    const float* __restrict__ wih2, const float* __restrict__ whh2,
    const float* __restrict__ bih2, const float* __restrict__ bhh2,
    const float* __restrict__ wih3, const float* __restrict__ whh3,
    const float* __restrict__ bih3, const float* __restrict__ bhh3,
    const float* __restrict__ l1w, const float* __restrict__ l1b,
    const float* __restrict__ l2w, const float* __restrict__ l2b,
    float* __restrict__ out, int Btot)
{
    // s_w[d][g][0..9] = W_hh row g; [10] = (g<20 ? b_ih+b_hh : b_hh); [11] = w_ih[g]
    __shared__ __align__(16) float s_w[4][30][12];
    __shared__ float s_bihn[4][10];                 // b_ih for n-gate rows (g=20..29)
    __shared__ __align__(16) float s_l1w[20][48];   // per-dir chunks at 12-float offsets, zero-padded
    __shared__ float s_l1b[20];
    __shared__ float s_l2w[2][20];
    __shared__ float s_l2b[2];

    const int tid = threadIdx.x;

#define STAGE_DIR(d, wihP, whhP, bihP, bhhP)                                  \
    for (int i = tid; i < 360; i += 256) {                                    \
        int g = i / 12, s = i % 12;                                           \
        float v;                                                              \
        if (s < 10)       v = whhP[g * 10 + s];                               \
        else if (s == 10) v = (g < 20) ? (bihP[g] + bhhP[g]) : bhhP[g];       \
        else              v = wihP[g];                                        \
        s_w[d][g][s] = v;                                                     \
    }                                                                         \
    for (int i = tid; i < 10; i += 256) s_bihn[d][i] = bihP[20 + i];

    STAGE_DIR(0, wih0, whh0, bih0, bhh0)
    STAGE_DIR(1, wih1, whh1, bih1, bhh1)
    STAGE_DIR(2, wih2, whh2, bih2, bhh2)
    STAGE_DIR(3, wih3, whh3, bih3, bhh3)
#undef STAGE_DIR
    for (int i = tid; i < 960; i += 256) {
        int o = i / 48, c = i % 48, dd = c / 12, jj = c % 12;
        s_l1w[o][c] = (jj < 10) ? l1w[o * 40 + dd * 10 + jj] : 0.0f;
    }
    for (int i = tid; i < 20; i += 256) s_l1b[i] = l1b[i];
    for (int i = tid; i < 40; i += 256) s_l2w[i / 20][i % 20] = l2w[i];
    for (int i = tid; i < 2; i += 256) s_l2b[i] = l2b[i];
    __syncthreads();

    const int gtid = blockIdx.x * 256 + tid;
    int row = gtid >> 2;
    const int d = tid & 3;            // direction: 0=g1 fwd, 1=g1 bwd, 2=g2 fwd, 3=g2 bwd
    const bool valid = (row < Btot);
    if (row >= Btot) row = Btot - 1;  // clamp (keep quad intact for shfl)

    // x sequence for this (row, dir): half = (d&2)?last5:first5, reversed if (d&1)
    float xq[5];
    {
        const float* srow = state + (size_t)row * 10 + ((d & 2) ? 5 : 0);
        const int rev = d & 1;
#pragma unroll
        for (int i = 0; i < 5; ++i) xq[i] = srow[rev ? (4 - i) : i];
    }

    const float* wb0 = &s_w[d][0][0];
    const float* bn0 = &s_bihn[d][0];

    float h[NH];
#pragma unroll
    for (int j = 0; j < NH; ++j) h[j] = 0.0f;

    unsigned hoff = 0;  // opaque 0: blocks LICM/CSE of the weight loads across t-steps
#pragma unroll 1
    for (int tt = 0; tt < 5; ++tt) {
        asm volatile("" : "+v"(hoff));
        const float* wb = wb0 + hoff;
        const float* bn = bn0 + hoff;
        const float xt = xq[0];
#pragma unroll
        for (int i = 0; i < 4; ++i) xq[i] = xq[i + 1];

        float hnew[NH];
#pragma unroll
        for (int j = 0; j < NH; ++j) {
            const float* wr = wb + j * 12;
            const float* wz = wb + (j + 10) * 12;
            const float* wn = wb + (j + 20) * 12;
            float4 r0 = *(const float4*)(wr), r1 = *(const float4*)(wr + 4), r2 = *(const float4*)(wr + 8);
            float ar = r2.z;                    // b_ih+b_hh (r)
            DOT10(ar, r0, r1, r2)
            ar = fmaf(r2.w, xt, ar);            // + w_ih*x
            float4 z0 = *(const float4*)(wz), z1 = *(const float4*)(wz + 4), z2 = *(const float4*)(wz + 8);
            float az = z2.z;
            DOT10(az, z0, z1, z2)
            az = fmaf(z2.w, xt, az);
            float4 n0 = *(const float4*)(wn), n1 = *(const float4*)(wn + 4), n2 = *(const float4*)(wn + 8);
            float an = n2.z;                    // b_hh only (n)
            DOT10(an, n0, n1, n2)
            float xn = fmaf(n2.w, xt, bn[j]);   // w_ih*x + b_ih
            float r = fsigmoid(ar);
            float z = fsigmoid(az);
            float n = ftanh(fmaf(r, an, xn));
            hnew[j] = fmaf(z, h[j] - n, n);     // (1-z)*n + z*h
        }
#pragma unroll
        for (int j = 0; j < NH; ++j) h[j] = hnew[j];
    }

    // partial l1: a1[o] = sum_j h[j] * l1w[o][d*10+j]  (padded layout, zero pad -> safe)
    float a1[20];
#pragma unroll
    for (int o = 0; o < 20; ++o) {
        const float* lw = &s_l1w[o][0] + d * 12;
        float4 c0 = *(const float4*)(lw), c1 = *(const float4*)(lw + 4), c2 = *(const float4*)(lw + 8);
        float s = 0.0f;
        DOT10(s, c0, c1, c2)
        a1[o] = s;
    }
    // quad reduce (dirs 0..3 of same row share lanes 4q..4q+3)
#pragma unroll
    for (int o = 0; o < 20; ++o) {
        a1[o] += __shfl_xor(a1[o], 1, 64);
        a1[o] += __shfl_xor(a1[o], 2, 64);
    }

    // SELU(l1 + bias), then l2 + clip (all lanes redundantly; lane d==0 stores)
    const float SC = 1.0507009873554805f;
    const float AL = 1.6732632423543772f;
    float o0 = s_l2b[0], o1 = s_l2b[1];
#pragma unroll
    for (int o = 0; o < 20; ++o) {
        float s = a1[o] + s_l1b[o];
        s = (s > 0.0f) ? SC * s : SC * AL * (fexp(s) - 1.0f);
        o0 = fmaf(s, s_l2w[0][o], o0);
        o1 = fmaf(s, s_l2w[1][o], o1);
    }
    o0 = fminf(1.0f, fmaxf(-1.0f, o0));
    o1 = fminf(1.0f, fmaxf(-1.0f, o1));

    if (valid && d == 0)
        reinterpret_cast<float2*>(out)[row] = make_float2(o0, o1);
}

extern "C" void kernel_launch(void* const* d_in, const int* in_sizes, int n_in,
                              void* d_out, int out_size, void* d_ws, size_t ws_size,
                              hipStream_t stream) {
    const float* state = (const float*)d_in[0];
    const int B = in_sizes[0] / 10;
    const long long threads = 4LL * B;
    const int grid = (int)((threads + 255) / 256);

    actor_kernel<<<grid, 256, 0, stream>>>(
        state,
        (const float*)d_in[1],  (const float*)d_in[2],  (const float*)d_in[3],  (const float*)d_in[4],
        (const float*)d_in[5],  (const float*)d_in[6],  (const float*)d_in[7],  (const float*)d_in[8],
        (const float*)d_in[9],  (const float*)d_in[10], (const float*)d_in[11], (const float*)d_in[12],
        (const float*)d_in[13], (const float*)d_in[14], (const float*)d_in[15], (const float*)d_in[16],
        (const float*)d_in[17], (const float*)d_in[18], (const float*)d_in[19], (const float*)d_in[20],
        (float*)d_out, B);
}

// Round 6
// 621.995 us; speedup vs baseline: 21.1541x; 1.0582x over previous
//
#include <hip/hip_runtime.h>

// Actor: state[B,10] -> 4x GRU dir(H=10,T=5,in=1) -> concat[40] -> l1(40->20,selu) -> l2(20->2) -> clip
// R6: pure fp32 (f16 failed accuracy in R4/R5), 4 lanes/row (one dir each) x 2 rows/lane so each
// ds_read_b128 weight load feeds two rows (R3 was LDS-issue bound: 510 b128/lane -> now 285).
// exp2 scale factors folded into staged weights (exact in fp32). Quad shfl reduce for l1.

#define NH 10

__device__ __forceinline__ float frcp(float x) { return __builtin_amdgcn_rcpf(x); }
__device__ __forceinline__ float fexp2(float x) { return __builtin_amdgcn_exp2f(x); }
__device__ __forceinline__ float fexp(float x) { return __expf(x); }

// acc += dot(w[0..9], hh[0..9]); c0=w0..3, c1=w4..7, c2.x=w8, c2.y=w9
#define DOT10(acc, c0, c1, c2, hh)                                     \
    acc = fmaf((c0).x, hh[0], acc); acc = fmaf((c0).y, hh[1], acc);    \
    acc = fmaf((c0).z, hh[2], acc); acc = fmaf((c0).w, hh[3], acc);    \
    acc = fmaf((c1).x, hh[4], acc); acc = fmaf((c1).y, hh[5], acc);    \
    acc = fmaf((c1).z, hh[6], acc); acc = fmaf((c1).w, hh[7], acc);    \
    acc = fmaf((c2).x, hh[8], acc); acc = fmaf((c2).y, hh[9], acc);

__global__ __launch_bounds__(256) void actor_kernel(
    const float* __restrict__ state,
    const float* __restrict__ wih0, const float* __restrict__ whh0,
    const float* __restrict__ bih0, const float* __restrict__ bhh0,
    const float* __restrict__ wih1, const float* __restrict__ whh1,
    const float* __restrict__ bih1, const float* __restrict__ bhh1,
    const float* __restrict__ wih2, const float* __restrict__ whh2,
    const float* __restrict__ bih2, const float* __restrict__ bhh2,
    const float* __restrict__ wih3, const float* __restrict__ whh3,
    const float* __restrict__ bih3, const float* __restrict__ bhh3,
    const float* __restrict__ l1w, const float* __restrict__ l1b,
    const float* __restrict__ l2w, const float* __restrict__ l2b,
    float* __restrict__ out, int Btot)
{
    // Row g (48B, 12 dwords): [0..9]=whh*sc, [10]=bias*sc ((bih+bhh) r/z, bhh n), [11]=wih*sc.
    // Dir stride 360 dwords -> quad lanes at bank offsets {0,8,16,24}: conflict-free b128.
    __shared__ __align__(16) float s_w[4][360];
    __shared__ float s_bihn[4][10];                 // bih n-gate * 2log2e
    __shared__ __align__(16) float s_l1w[20][48];   // per-dir 12-dword chunks, zero-padded
    __shared__ float s_l1b[20];
    __shared__ float s_l2w[2][20];
    __shared__ float s_l2b[2];

    const int tid = threadIdx.x;
    const float NL2E = -1.4426950408889634f;   // -log2(e)   (r,z rows)
    const float P2L2E = 2.8853900817779268f;   // 2*log2(e)  (n rows)

#define STAGE_DIR(d, wihP, whhP, bihP, bhhP)                                   \
    for (int i = tid; i < 360; i += 256) {                                     \
        int g = i / 12, s = i % 12;                                            \
        float sc = (g < 20) ? NL2E : P2L2E;                                    \
        float v;                                                               \
        if (s < 10)       v = whhP[g * 10 + s] * sc;                           \
        else if (s == 10) v = ((g < 20) ? (bihP[g] + bhhP[g]) : bhhP[g]) * sc; \
        else              v = wihP[g] * sc;                                    \
        s_w[d][g * 12 + s] = v;                                                \
    }                                                                          \
    for (int i = tid; i < 10; i += 256) s_bihn[d][i] = bihP[20 + i] * P2L2E;

    STAGE_DIR(0, wih0, whh0, bih0, bhh0)
    STAGE_DIR(1, wih1, whh1, bih1, bhh1)
    STAGE_DIR(2, wih2, whh2, bih2, bhh2)
    STAGE_DIR(3, wih3, whh3, bih3, bhh3)
#undef STAGE_DIR
    for (int i = tid; i < 960; i += 256) {
        int o = i / 48, c = i % 48, dd = c / 12, jj = c % 12;
        s_l1w[o][c] = (jj < 10) ? l1w[o * 40 + dd * 10 + jj] : 0.0f;
    }
    for (int i = tid; i < 20; i += 256) s_l1b[i] = l1b[i];
    for (int i = tid; i < 40; i += 256) s_l2w[i / 20][i % 20] = l2w[i];
    for (int i = tid; i < 2; i += 256) s_l2b[i] = l2b[i];
    __syncthreads();

    const int q = tid >> 2;
    const int d = tid & 3;            // 0=g1 fwd, 1=g1 bwd, 2=g2 fwd, 3=g2 bwd
    long long rA = (long long)blockIdx.x * 128 + 2 * q;   // this lane's two rows
    long long rB = rA + 1;
    const bool vA = (rA < Btot), vB = (rB < Btot);
    if (rA >= Btot) rA = Btot - 1;
    if (rB >= Btot) rB = Btot - 1;

    // x sequences (half = (d&2)?last5:first5, reversed if d&1)
    float xqA[5], xqB[5];
    {
        const float* pA = state + rA * 10 + ((d & 2) ? 5 : 0);
        const float* pB = state + rB * 10 + ((d & 2) ? 5 : 0);
        const int rev = d & 1;
#pragma unroll
        for (int i = 0; i < 5; ++i) {
            xqA[i] = pA[rev ? (4 - i) : i];
            xqB[i] = pB[rev ? (4 - i) : i];
        }
    }

    const float* wb0 = &s_w[d][0];
    const float* bn  = &s_bihn[d][0];

    float hA[NH], hB[NH];
#pragma unroll
    for (int j = 0; j < NH; ++j) { hA[j] = 0.0f; hB[j] = 0.0f; }

    unsigned hoff = 0;  // opaque 0: blocks LICM/CSE of weight loads across t-steps
#pragma unroll 1
    for (int tt = 0; tt < 5; ++tt) {
        asm volatile("" : "+v"(hoff));
        const float* wb = wb0 + hoff;
        const float xtA = xqA[0], xtB = xqB[0];
#pragma unroll
        for (int i = 0; i < 4; ++i) { xqA[i] = xqA[i + 1]; xqB[i] = xqB[i + 1]; }

        float hnA[NH], hnB[NH];
#pragma unroll
        for (int j = 0; j < NH; ++j) {
            const float* rp = wb + j * 12;
            const float* zp = wb + (j + 10) * 12;
            const float* np = wb + (j + 20) * 12;
            float4 r0 = *(const float4*)rp, r1 = *(const float4*)(rp + 4), r2 = *(const float4*)(rp + 8);
            float4 z0 = *(const float4*)zp, z1 = *(const float4*)(zp + 4), z2 = *(const float4*)(zp + 8);
            float4 n0 = *(const float4*)np, n1 = *(const float4*)(np + 4), n2 = *(const float4*)(np + 8);

            float arA = fmaf(r2.w, xtA, r2.z), arB = fmaf(r2.w, xtB, r2.z);
            DOT10(arA, r0, r1, r2, hA)  DOT10(arB, r0, r1, r2, hB)
            float azA = fmaf(z2.w, xtA, z2.z), azB = fmaf(z2.w, xtB, z2.z);
            DOT10(azA, z0, z1, z2, hA)  DOT10(azB, z0, z1, z2, hB)
            float anA = n2.z, anB = n2.z;
            DOT10(anA, n0, n1, n2, hA)  DOT10(anB, n0, n1, n2, hB)

            float rrA = frcp(1.0f + fexp2(arA)), rrB = frcp(1.0f + fexp2(arB));
            float zzA = frcp(1.0f + fexp2(azA)), zzB = frcp(1.0f + fexp2(azB));
            float xnA = fmaf(n2.w, xtA, bn[j]), xnB = fmaf(n2.w, xtB, bn[j]);
            float eA = fexp2(fmaf(rrA, anA, xnA)), eB = fexp2(fmaf(rrB, anB, xnB));
            float nnA = fmaf(-2.0f, frcp(eA + 1.0f), 1.0f);
            float nnB = fmaf(-2.0f, frcp(eB + 1.0f), 1.0f);
            hnA[j] = fmaf(zzA, hA[j] - nnA, nnA);   // (1-z)*n + z*h
            hnB[j] = fmaf(zzB, hB[j] - nnB, nnB);
        }
#pragma unroll
        for (int j = 0; j < NH; ++j) { hA[j] = hnA[j]; hB[j] = hnB[j]; }
    }

    // partial l1 for both rows (zero-padded layout), then quad reduce
    float a1A[20], a1B[20];
#pragma unroll
    for (int o = 0; o < 20; ++o) {
        const float* lw = &s_l1w[o][0] + d * 12;
        float4 c0 = *(const float4*)(lw), c1 = *(const float4*)(lw + 4), c2 = *(const float4*)(lw + 8);
        float sA = 0.0f, sB = 0.0f;
        DOT10(sA, c0, c1, c2, hA)
        DOT10(sB, c0, c1, c2, hB)
        a1A[o] = sA; a1B[o] = sB;
    }
#pragma unroll
    for (int o = 0; o < 20; ++o) {
        a1A[o] += __shfl_xor(a1A[o], 1, 64);
        a1A[o] += __shfl_xor(a1A[o], 2, 64);
        a1B[o] += __shfl_xor(a1B[o], 1, 64);
        a1B[o] += __shfl_xor(a1B[o], 2, 64);
    }

    // SELU + l2 + clip (all quad lanes redundantly; lane d==0 stores)
    const float SC = 1.0507009873554805f;
    const float AL = 1.6732632423543772f;
    float o0A = s_l2b[0], o1A = s_l2b[1], o0B = s_l2b[0], o1B = s_l2b[1];
#pragma unroll
    for (int o = 0; o < 20; ++o) {
        float sA = a1A[o] + s_l1b[o];
        sA = (sA > 0.0f) ? SC * sA : SC * AL * (fexp(sA) - 1.0f);
        o0A = fmaf(sA, s_l2w[0][o], o0A);
        o1A = fmaf(sA, s_l2w[1][o], o1A);
        float sB = a1B[o] + s_l1b[o];
        sB = (sB > 0.0f) ? SC * sB : SC * AL * (fexp(sB) - 1.0f);
        o0B = fmaf(sB, s_l2w[0][o], o0B);
        o1B = fmaf(sB, s_l2w[1][o], o1B);
    }
    o0A = fminf(1.0f, fmaxf(-1.0f, o0A));
    o1A = fminf(1.0f, fmaxf(-1.0f, o1A));
    o0B = fminf(1.0f, fmaxf(-1.0f, o0B));
    o1B = fminf(1.0f, fmaxf(-1.0f, o1B));

    if (d == 0) {
        if (vA && vB) {
            *reinterpret_cast<float4*>(out + rA * 2) = make_float4(o0A, o1A, o0B, o1B);
        } else {
            if (vA) reinterpret_cast<float2*>(out)[rA] = make_float2(o0A, o1A);
            if (vB) reinterpret_cast<float2*>(out)[rB] = make_float2(o0B, o1B);
        }
    }
}

extern "C" void kernel_launch(void* const* d_in, const int* in_sizes, int n_in,
                              void* d_out, int out_size, void* d_ws, size_t ws_size,
                              hipStream_t stream) {
    const float* state = (const float*)d_in[0];
    const int B = in_sizes[0] / 10;
    const int grid = (B + 127) / 128;   // 128 rows per 256-thread block (2 rows per lane-quad)

    actor_kernel<<<grid, 256, 0, stream>>>(
        state,
        (const float*)d_in[1],  (const float*)d_in[2],  (const float*)d_in[3],  (const float*)d_in[4],
        (const float*)d_in[5],  (const float*)d_in[6],  (const float*)d_in[7],  (const float*)d_in[8],
        (const float*)d_in[9],  (const float*)d_in[10], (const float*)d_in[11], (const float*)d_in[12],
        (const float*)d_in[13], (const float*)d_in[14], (const float*)d_in[15], (const float*)d_in[16],
        (const float*)d_in[17], (const float*)d_in[18], (const float*)d_in[19], (const float*)d_in[20],
        (float*)d_out, B);
}

// Round 7
// 555.501 us; speedup vs baseline: 23.6862x; 1.1197x over previous
//
#include <hip/hip_runtime.h>

// Actor: state[B,10] -> 4x GRU dir(H=10,T=5,in=1) -> concat[40] -> l1(40->20,selu) -> l2(20->2) -> clip
// R7: R6 structure (fp32, 4 lanes/row x 2 rows/lane) but all dot products via v_pk_fma_f32
// (2 IEEE fp32 FMA/instr). Rows A,B packed in VGPR pairs; scalar weights broadcast straight
// from ds_read_b128 quads via op_sel/op_sel_hi (even-aligned subreg pairs, no dup movs).

#define NH 10

typedef float f32x2 __attribute__((ext_vector_type(2)));
struct __align__(16) q2 { f32x2 lo, hi; };   // one ds_read_b128 = two even-aligned pairs

__device__ __forceinline__ float frcp(float x) { return __builtin_amdgcn_rcpf(x); }
__device__ __forceinline__ float fexp2(float x) { return __builtin_amdgcn_exp2f(x); }
__device__ __forceinline__ float fexp(float x) { return __expf(x); }

// d = a * b.lo + c   (per half: lo: a.lo*b.lo+c.lo ; hi: a.hi*b.lo+c.hi)
__device__ __forceinline__ f32x2 pk_fma_lo(f32x2 a, f32x2 b, f32x2 c) {
    f32x2 d;
    asm("v_pk_fma_f32 %0, %1, %2, %3 op_sel_hi:[1,0,1]" : "=v"(d) : "v"(a), "v"(b), "v"(c));
    return d;
}
// d = a * b.hi + c
__device__ __forceinline__ f32x2 pk_fma_hi(f32x2 a, f32x2 b, f32x2 c) {
    f32x2 d;
    asm("v_pk_fma_f32 %0, %1, %2, %3 op_sel:[0,1,0] op_sel_hi:[1,1,1]" : "=v"(d) : "v"(a), "v"(b), "v"(c));
    return d;
}
// d = a * b.hi + c.lo   (bias-init: xt*wih + bias, bias in c.lo)
__device__ __forceinline__ f32x2 pk_fma_bh_cl(f32x2 a, f32x2 b, f32x2 c) {
    f32x2 d;
    asm("v_pk_fma_f32 %0, %1, %2, %3 op_sel:[0,1,0] op_sel_hi:[1,1,0]" : "=v"(d) : "v"(a), "v"(b), "v"(c));
    return d;
}
// d = a * b.lo + c.lo
__device__ __forceinline__ f32x2 pk_fma_bl_cl(f32x2 a, f32x2 b, f32x2 c) {
    f32x2 d;
    asm("v_pk_fma_f32 %0, %1, %2, %3 op_sel_hi:[1,0,0]" : "=v"(d) : "v"(a), "v"(b), "v"(c));
    return d;
}
// full packed d = a*b + c
__device__ __forceinline__ f32x2 pk_fma(f32x2 a, f32x2 b, f32x2 c) {
    f32x2 d;
    asm("v_pk_fma_f32 %0, %1, %2, %3" : "=v"(d) : "v"(a), "v"(b), "v"(c));
    return d;
}

// acc += dot(w[1..9], hh[1..9]) given quads q1=(w0..3) q2=(w4..7) q3=(w8,w9,-,-)
#define PDOT9(acc, hh, q1, q2_, q3)                  \
    acc = pk_fma_hi(hh[1], (q1).lo, acc);            \
    acc = pk_fma_lo(hh[2], (q1).hi, acc);            \
    acc = pk_fma_hi(hh[3], (q1).hi, acc);            \
    acc = pk_fma_lo(hh[4], (q2_).lo, acc);           \
    acc = pk_fma_hi(hh[5], (q2_).lo, acc);           \
    acc = pk_fma_lo(hh[6], (q2_).hi, acc);           \
    acc = pk_fma_hi(hh[7], (q2_).hi, acc);           \
    acc = pk_fma_lo(hh[8], (q3).lo, acc);            \
    acc = pk_fma_hi(hh[9], (q3).lo, acc);

#define LDQ(p) (*(const q2*)(p))

__global__ __launch_bounds__(256) void actor_kernel(
    const float* __restrict__ state,
    const float* __restrict__ wih0, const float* __restrict__ whh0,
    const float* __restrict__ bih0, const float* __restrict__ bhh0,
    const float* __restrict__ wih1, const float* __restrict__ whh1,
    const float* __restrict__ bih1, const float* __restrict__ bhh1,
    const float* __restrict__ wih2, const float* __restrict__ whh2,
    const float* __restrict__ bih2, const float* __restrict__ bhh2,
    const float* __restrict__ wih3, const float* __restrict__ whh3,
    const float* __restrict__ bih3, const float* __restrict__ bhh3,
    const float* __restrict__ l1w, const float* __restrict__ l1b,
    const float* __restrict__ l2w, const float* __restrict__ l2b,
    float* __restrict__ out, int Btot)
{
    // Row g (48B): [0..9]=whh*sc, [10]=bias*sc ((bih+bhh) r/z, bhh n), [11]=wih*sc.
    // Dir stride 360 dwords -> quad lanes at bank offsets {0,8,16,24}: conflict-free b128.
    __shared__ __align__(16) float s_w[4][360];
    __shared__ __align__(8) f32x2 s_bihn2[4][10];   // bih n-gate * 2log2e, duplicated {v,v}
    __shared__ __align__(16) float s_l1w[20][48];   // per-dir 12-dword chunks, zero-padded
    __shared__ float s_l1b[20];
    __shared__ __align__(8) f32x2 s_l2w2[2][20];    // duplicated {v,v}
    __shared__ float s_l2b[2];

    const int tid = threadIdx.x;
    const float NL2E = -1.4426950408889634f;   // -log2(e)   (r,z rows)
    const float P2L2E = 2.8853900817779268f;   // 2*log2(e)  (n rows)

#define STAGE_DIR(d, wihP, whhP, bihP, bhhP)                                   \
    for (int i = tid; i < 360; i += 256) {                                     \
        int g = i / 12, s = i % 12;                                            \
        float sc = (g < 20) ? NL2E : P2L2E;                                    \
        float v;                                                               \
        if (s < 10)       v = whhP[g * 10 + s] * sc;                           \
        else if (s == 10) v = ((g < 20) ? (bihP[g] + bhhP[g]) : bhhP[g]) * sc; \
        else              v = wihP[g] * sc;                                    \
        s_w[d][g * 12 + s] = v;                                                \
    }                                                                          \
    for (int i = tid; i < 10; i += 256) {                                      \
        float v = bihP[20 + i] * P2L2E;                                        \
        s_bihn2[d][i] = (f32x2){v, v};                                         \
    }

    STAGE_DIR(0, wih0, whh0, bih0, bhh0)
    STAGE_DIR(1, wih1, whh1, bih1, bhh1)
    STAGE_DIR(2, wih2, whh2, bih2, bhh2)
    STAGE_DIR(3, wih3, whh3, bih3, bhh3)
#undef STAGE_DIR
    for (int i = tid; i < 960; i += 256) {
        int o = i / 48, c = i % 48, dd = c / 12, jj = c % 12;
        s_l1w[o][c] = (jj < 10) ? l1w[o * 40 + dd * 10 + jj] : 0.0f;
    }
    for (int i = tid; i < 20; i += 256) s_l1b[i] = l1b[i];
    for (int i = tid; i < 40; i += 256) {
        float v = l2w[i];
        s_l2w2[i / 20][i % 20] = (f32x2){v, v};
    }
    for (int i = tid; i < 2; i += 256) s_l2b[i] = l2b[i];
    __syncthreads();

    const int q = tid >> 2;
    const int d = tid & 3;            // 0=g1 fwd, 1=g1 bwd, 2=g2 fwd, 3=g2 bwd
    long long rA = (long long)blockIdx.x * 128 + 2 * q;   // this lane's two rows
    long long rB = rA + 1;
    const bool vA = (rA < Btot), vB = (rB < Btot);
    if (rA >= Btot) rA = Btot - 1;
    if (rB >= Btot) rB = Btot - 1;

    // packed x queue: xq2[i] = (x_t for row A, row B)
    f32x2 xq2[5];
    {
        const float* pA = state + rA * 10 + ((d & 2) ? 5 : 0);
        const float* pB = state + rB * 10 + ((d & 2) ? 5 : 0);
        const int rev = d & 1;
#pragma unroll
        for (int i = 0; i < 5; ++i) {
            int k = rev ? (4 - i) : i;
            xq2[i] = (f32x2){pA[k], pB[k]};
        }
    }

    const float* wb0 = &s_w[d][0];
    const f32x2* bn2 = &s_bihn2[d][0];

    f32x2 h2[NH];
#pragma unroll
    for (int j = 0; j < NH; ++j) h2[j] = (f32x2){0.0f, 0.0f};

    unsigned hoff = 0;  // opaque 0: blocks LICM/CSE of weight loads across t-steps
#pragma unroll 1
    for (int tt = 0; tt < 5; ++tt) {
        asm volatile("" : "+v"(hoff));
        const float* wb = wb0 + hoff;
        const f32x2 xt2 = xq2[0];
#pragma unroll
        for (int i = 0; i < 4; ++i) xq2[i] = xq2[i + 1];

        f32x2 hn2[NH];
#pragma unroll
        for (int j = 0; j < NH; ++j) {
            const float* rp = wb + j * 12;
            const float* zp = wb + (j + 10) * 12;
            const float* np = wb + (j + 20) * 12;
            q2 rq0 = LDQ(rp), rq1 = LDQ(rp + 4), rq2 = LDQ(rp + 8);
            q2 zq0 = LDQ(zp), zq1 = LDQ(zp + 4), zq2 = LDQ(zp + 8);
            q2 nq0 = LDQ(np), nq1 = LDQ(np + 4), nq2 = LDQ(np + 8);

            // ar = xt*wih + bias + W.h   (quad3.hi = (bias, wih))
            f32x2 ar = pk_fma_bh_cl(xt2, rq2.hi, rq2.hi);
            ar = pk_fma_lo(h2[0], rq0.lo, ar);
            PDOT9(ar, h2, rq0, rq1, rq2)
            f32x2 az = pk_fma_bh_cl(xt2, zq2.hi, zq2.hi);
            az = pk_fma_lo(h2[0], zq0.lo, az);
            PDOT9(az, h2, zq0, zq1, zq2)
            // an = bhh + W.h  (no wih term inside)
            f32x2 an = pk_fma_bl_cl(h2[0], nq0.lo, nq2.hi);
            PDOT9(an, h2, nq0, nq1, nq2)
            // xn = xt*wih + bih_n
            f32x2 xn = pk_fma_bh_cl(xt2, nq2.hi, bn2[j]);

            f32x2 rr, zz, e, nn;
            rr.x = frcp(1.0f + fexp2(ar.x)); rr.y = frcp(1.0f + fexp2(ar.y));
            zz.x = frcp(1.0f + fexp2(az.x)); zz.y = frcp(1.0f + fexp2(az.y));
            e.x = fexp2(fmaf(rr.x, an.x, xn.x)); e.y = fexp2(fmaf(rr.y, an.y, xn.y));
            nn.x = fmaf(-2.0f, frcp(e.x + 1.0f), 1.0f);
            nn.y = fmaf(-2.0f, frcp(e.y + 1.0f), 1.0f);
            f32x2 t = h2[j] - nn;
            hn2[j] = pk_fma(zz, t, nn);          // (1-z)*n + z*h
        }
#pragma unroll
        for (int j = 0; j < NH; ++j) h2[j] = hn2[j];
    }

    // partial l1 (packed): a1[o] = sum_j h[j] * l1w[o][d*10+j]; quad3.hi = (0,0) zero pad
    f32x2 a1[20];
#pragma unroll
    for (int o = 0; o < 20; ++o) {
        const float* lw = &s_l1w[o][0] + d * 12;
        q2 c0 = LDQ(lw), c1 = LDQ(lw + 4), c2 = LDQ(lw + 8);
        f32x2 s = pk_fma_bl_cl(h2[0], c0.lo, c2.hi);   // h0*w0 + 0
        PDOT9(s, h2, c0, c1, c2)
        a1[o] = s;
    }
    // quad reduce (component-wise shfl)
#pragma unroll
    for (int o = 0; o < 20; ++o) {
        f32x2 v = a1[o];
        v.x += __shfl_xor(v.x, 1, 64);
        v.x += __shfl_xor(v.x, 2, 64);
        v.y += __shfl_xor(v.y, 1, 64);
        v.y += __shfl_xor(v.y, 2, 64);
        a1[o] = v;
    }

    // SELU + l2 + clip (packed across rows; all quad lanes redundant; lane d==0 stores)
    const float SC = 1.0507009873554805f;
    const float AL = 1.6732632423543772f;
    f32x2 o0 = (f32x2){s_l2b[0], s_l2b[0]};
    f32x2 o1 = (f32x2){s_l2b[1], s_l2b[1]};
#pragma unroll
    for (int o = 0; o < 20; ++o) {
        f32x2 s;
        s.x = a1[o].x + s_l1b[o];
        s.y = a1[o].y + s_l1b[o];
        s.x = (s.x > 0.0f) ? SC * s.x : SC * AL * (fexp(s.x) - 1.0f);
        s.y = (s.y > 0.0f) ? SC * s.y : SC * AL * (fexp(s.y) - 1.0f);
        o0 = pk_fma_lo(s, s_l2w2[0][o], o0);
        o1 = pk_fma_lo(s, s_l2w2[1][o], o1);
    }
    o0.x = fminf(1.0f, fmaxf(-1.0f, o0.x));
    o0.y = fminf(1.0f, fmaxf(-1.0f, o0.y));
    o1.x = fminf(1.0f, fmaxf(-1.0f, o1.x));
    o1.y = fminf(1.0f, fmaxf(-1.0f, o1.y));

    if (d == 0) {
        if (vA && vB) {
            *reinterpret_cast<float4*>(out + rA * 2) = make_float4(o0.x, o1.x, o0.y, o1.y);
        } else {
            if (vA) reinterpret_cast<float2*>(out)[rA] = make_float2(o0.x, o1.x);
            if (vB) reinterpret_cast<float2*>(out)[rB] = make_float2(o0.y, o1.y);
        }
    }
}

extern "C" void kernel_launch(void* const* d_in, const int* in_sizes, int n_in,
                              void* d_out, int out_size, void* d_ws, size_t ws_size,
                              hipStream_t stream) {
    const float* state = (const float*)d_in[0];
    const int B = in_sizes[0] / 10;
    const int grid = (B + 127) / 128;   // 128 rows per 256-thread block (2 rows per lane-quad)

    actor_kernel<<<grid, 256, 0, stream>>>(
        state,
        (const float*)d_in[1],  (const float*)d_in[2],  (const float*)d_in[3],  (const float*)d_in[4],
        (const float*)d_in[5],  (const float*)d_in[6],  (const float*)d_in[7],  (const float*)d_in[8],
        (const float*)d_in[9],  (const float*)d_in[10], (const float*)d_in[11], (const float*)d_in[12],
        (const float*)d_in[13], (const float*)d_in[14], (const float*)d_in[15], (const float*)d_in[16],
        (const float*)d_in[17], (const float*)d_in[18], (const float*)d_in[19], (const float*)d_in[20],
        (float*)d_out, B);
}

// Round 8
// 507.356 us; speedup vs baseline: 25.9339x; 1.0949x over previous
//
#include <hip/hip_runtime.h>

// Actor: state[B,10] -> 4x GRU dir(H=10,T=5,in=1) -> concat[40] -> l1(40->20,selu) -> l2(20->2) -> clip
// R8: fp32, 4 lanes/row-quad (one dir each) x 4 rows/lane (two f32x2 pairs) so each
// ds_read_b128 weight quad feeds 4 rows. v_pk_fma_f32 everywhere (half-rate but halves
// instruction count). Streaming epilogue (no a1[] array): per-o partial -> quad butterfly
// -> SELU -> l2 accumulate, keeps live set ~140 VGPR.

#define NH 10

typedef float f32x2 __attribute__((ext_vector_type(2)));
struct __align__(16) q2 { f32x2 lo, hi; };   // one ds_read_b128 = two even-aligned pairs

__device__ __forceinline__ float frcp(float x) { return __builtin_amdgcn_rcpf(x); }
__device__ __forceinline__ float fexp2(float x) { return __builtin_amdgcn_exp2f(x); }
__device__ __forceinline__ float fexp(float x) { return __expf(x); }

// d = a * b.lo + c
__device__ __forceinline__ f32x2 pk_fma_lo(f32x2 a, f32x2 b, f32x2 c) {
    f32x2 d;
    asm("v_pk_fma_f32 %0, %1, %2, %3 op_sel_hi:[1,0,1]" : "=v"(d) : "v"(a), "v"(b), "v"(c));
    return d;
}
// d = a * b.hi + c
__device__ __forceinline__ f32x2 pk_fma_hi(f32x2 a, f32x2 b, f32x2 c) {
    f32x2 d;
    asm("v_pk_fma_f32 %0, %1, %2, %3 op_sel:[0,1,0] op_sel_hi:[1,1,1]" : "=v"(d) : "v"(a), "v"(b), "v"(c));
    return d;
}
// d = a * b.hi + c.lo   (bias-init: xt*wih + bias, bias in c.lo)
__device__ __forceinline__ f32x2 pk_fma_bh_cl(f32x2 a, f32x2 b, f32x2 c) {
    f32x2 d;
    asm("v_pk_fma_f32 %0, %1, %2, %3 op_sel:[0,1,0] op_sel_hi:[1,1,0]" : "=v"(d) : "v"(a), "v"(b), "v"(c));
    return d;
}
// d = a * b.lo + c.lo
__device__ __forceinline__ f32x2 pk_fma_bl_cl(f32x2 a, f32x2 b, f32x2 c) {
    f32x2 d;
    asm("v_pk_fma_f32 %0, %1, %2, %3 op_sel_hi:[1,0,0]" : "=v"(d) : "v"(a), "v"(b), "v"(c));
    return d;
}
// full packed d = a*b + c
__device__ __forceinline__ f32x2 pk_fma(f32x2 a, f32x2 b, f32x2 c) {
    f32x2 d;
    asm("v_pk_fma_f32 %0, %1, %2, %3" : "=v"(d) : "v"(a), "v"(b), "v"(c));
    return d;
}

// acc += dot(w[1..9], hh[1..9]) given quads q1=(w0..3) q2_=(w4..7) q3=(w8,w9,-,-)
#define PDOT9(acc, hh, q1, q2_, q3)                  \
    acc = pk_fma_hi(hh[1], (q1).lo, acc);            \
    acc = pk_fma_lo(hh[2], (q1).hi, acc);            \
    acc = pk_fma_hi(hh[3], (q1).hi, acc);            \
    acc = pk_fma_lo(hh[4], (q2_).lo, acc);           \
    acc = pk_fma_hi(hh[5], (q2_).lo, acc);           \
    acc = pk_fma_lo(hh[6], (q2_).hi, acc);           \
    acc = pk_fma_hi(hh[7], (q2_).hi, acc);           \
    acc = pk_fma_lo(hh[8], (q3).lo, acc);            \
    acc = pk_fma_hi(hh[9], (q3).lo, acc);

#define LDQ(p) (*(const q2*)(p))

__global__ __launch_bounds__(256) void actor_kernel(
    const float* __restrict__ state,
    const float* __restrict__ wih0, const float* __restrict__ whh0,
    const float* __restrict__ bih0, const float* __restrict__ bhh0,
    const float* __restrict__ wih1, const float* __restrict__ whh1,
    const float* __restrict__ bih1, const float* __restrict__ bhh1,
    const float* __restrict__ wih2, const float* __restrict__ whh2,
    const float* __restrict__ bih2, const float* __restrict__ bhh2,
    const float* __restrict__ wih3, const float* __restrict__ whh3,
    const float* __restrict__ bih3, const float* __restrict__ bhh3,
    const float* __restrict__ l1w, const float* __restrict__ l1b,
    const float* __restrict__ l2w, const float* __restrict__ l2b,
    float* __restrict__ out, int Btot)
{
    // Row g (48B): [0..9]=whh*sc, [10]=bias*sc ((bih+bhh) r/z, bhh n), [11]=wih*sc.
    // Dir stride 360 dwords -> quad lanes at bank offsets {0,8,16,24}: conflict-free b128.
    __shared__ __align__(16) float s_w[4][360];
    __shared__ __align__(8) f32x2 s_bihn2[4][10];   // bih n-gate * 2log2e, duplicated {v,v}
    __shared__ __align__(16) float s_l1w[20][48];   // per-dir 12-dword chunks, zero-padded
    __shared__ float s_l1b[20];
    __shared__ __align__(8) f32x2 s_l2w2[2][20];    // duplicated {v,v}
    __shared__ float s_l2b[2];

    const int tid = threadIdx.x;
    const float NL2E = -1.4426950408889634f;   // -log2(e)   (r,z rows)
    const float P2L2E = 2.8853900817779268f;   // 2*log2(e)  (n rows)

#define STAGE_DIR(d, wihP, whhP, bihP, bhhP)                                   \
    for (int i = tid; i < 360; i += 256) {                                     \
        int g = i / 12, s = i % 12;                                            \
        float sc = (g < 20) ? NL2E : P2L2E;                                    \
        float v;                                                               \
        if (s < 10)       v = whhP[g * 10 + s] * sc;                           \
        else if (s == 10) v = ((g < 20) ? (bihP[g] + bhhP[g]) : bhhP[g]) * sc; \
        else              v = wihP[g] * sc;                                    \
        s_w[d][g * 12 + s] = v;                                                \
    }                                                                          \
    for (int i = tid; i < 10; i += 256) {                                      \
        float v = bihP[20 + i] * P2L2E;                                        \
        s_bihn2[d][i] = (f32x2){v, v};                                         \
    }

    STAGE_DIR(0, wih0, whh0, bih0, bhh0)
    STAGE_DIR(1, wih1, whh1, bih1, bhh1)
    STAGE_DIR(2, wih2, whh2, bih2, bhh2)
    STAGE_DIR(3, wih3, whh3, bih3, bhh3)
#undef STAGE_DIR
    for (int i = tid; i < 960; i += 256) {
        int o = i / 48, c = i % 48, dd = c / 12, jj = c % 12;
        s_l1w[o][c] = (jj < 10) ? l1w[o * 40 + dd * 10 + jj] : 0.0f;
    }
    for (int i = tid; i < 20; i += 256) s_l1b[i] = l1b[i];
    for (int i = tid; i < 40; i += 256) {
        float v = l2w[i];
        s_l2w2[i / 20][i % 20] = (f32x2){v, v};
    }
    for (int i = tid; i < 2; i += 256) s_l2b[i] = l2b[i];
    __syncthreads();

    const int q = tid >> 2;
    const int d = tid & 3;            // 0=g1 fwd, 1=g1 bwd, 2=g2 fwd, 3=g2 bwd
    // 4 rows per lane: pair P = {base, base+1}, pair Q = {base+2, base+3}
    long long base = (long long)blockIdx.x * 256 + 4 * q;
    long long r0 = base, r1 = base + 1, r2 = base + 2, r3 = base + 3;
    const bool v01 = (r1 < Btot), v23 = (r3 < Btot);
    if (r0 >= Btot) r0 = Btot - 1;
    if (r1 >= Btot) r1 = Btot - 1;
    if (r2 >= Btot) r2 = Btot - 1;
    if (r3 >= Btot) r3 = Btot - 1;

    // packed x queues
    f32x2 xqp[5], xqq[5];
    {
        const int off = (d & 2) ? 5 : 0;
        const float* p0 = state + r0 * 10 + off;
        const float* p1 = state + r1 * 10 + off;
        const float* p2 = state + r2 * 10 + off;
        const float* p3 = state + r3 * 10 + off;
        const int rev = d & 1;
#pragma unroll
        for (int i = 0; i < 5; ++i) {
            int k = rev ? (4 - i) : i;
            xqp[i] = (f32x2){p0[k], p1[k]};
            xqq[i] = (f32x2){p2[k], p3[k]};
        }
    }

    const float* wb0 = &s_w[d][0];
    const f32x2* bn2 = &s_bihn2[d][0];

    f32x2 hp[NH], hq[NH];
#pragma unroll
    for (int j = 0; j < NH; ++j) { hp[j] = (f32x2){0.0f, 0.0f}; hq[j] = (f32x2){0.0f, 0.0f}; }

    unsigned hoff = 0;  // opaque 0: blocks LICM/CSE of weight loads across t-steps
#pragma unroll 1
    for (int tt = 0; tt < 5; ++tt) {
        asm volatile("" : "+v"(hoff));
        const float* wb = wb0 + hoff;
        const f32x2 xtp = xqp[0], xtq = xqq[0];
#pragma unroll
        for (int i = 0; i < 4; ++i) { xqp[i] = xqp[i + 1]; xqq[i] = xqq[i + 1]; }

        f32x2 hnp[NH], hnq[NH];
#pragma unroll
        for (int j = 0; j < NH; ++j) {
            const float* rp = wb + j * 12;
            const float* zp = wb + (j + 10) * 12;
            const float* np = wb + (j + 20) * 12;
            q2 rq0 = LDQ(rp), rq1 = LDQ(rp + 4), rq2 = LDQ(rp + 8);
            q2 zq0 = LDQ(zp), zq1 = LDQ(zp + 4), zq2 = LDQ(zp + 8);
            q2 nq0 = LDQ(np), nq1 = LDQ(np + 4), nq2 = LDQ(np + 8);
            const f32x2 bnj = bn2[j];

            // pair P
            f32x2 arP = pk_fma_bh_cl(xtp, rq2.hi, rq2.hi);
            arP = pk_fma_lo(hp[0], rq0.lo, arP);
            PDOT9(arP, hp, rq0, rq1, rq2)
            f32x2 azP = pk_fma_bh_cl(xtp, zq2.hi, zq2.hi);
            azP = pk_fma_lo(hp[0], zq0.lo, azP);
            PDOT9(azP, hp, zq0, zq1, zq2)
            f32x2 anP = pk_fma_bl_cl(hp[0], nq0.lo, nq2.hi);
            PDOT9(anP, hp, nq0, nq1, nq2)
            f32x2 xnP = pk_fma_bh_cl(xtp, nq2.hi, bnj);

            // pair Q (reuses the 9 loaded quads)
            f32x2 arQ = pk_fma_bh_cl(xtq, rq2.hi, rq2.hi);
            arQ = pk_fma_lo(hq[0], rq0.lo, arQ);
            PDOT9(arQ, hq, rq0, rq1, rq2)
            f32x2 azQ = pk_fma_bh_cl(xtq, zq2.hi, zq2.hi);
            azQ = pk_fma_lo(hq[0], zq0.lo, azQ);
            PDOT9(azQ, hq, zq0, zq1, zq2)
            f32x2 anQ = pk_fma_bl_cl(hq[0], nq0.lo, nq2.hi);
            PDOT9(anQ, hq, nq0, nq1, nq2)
            f32x2 xnQ = pk_fma_bh_cl(xtq, nq2.hi, bnj);

            f32x2 rrP, zzP, eP, nnP, rrQ, zzQ, eQ, nnQ;
            rrP.x = frcp(1.0f + fexp2(arP.x)); rrP.y = frcp(1.0f + fexp2(arP.y));
            zzP.x = frcp(1.0f + fexp2(azP.x)); zzP.y = frcp(1.0f + fexp2(azP.y));
            eP.x = fexp2(fmaf(rrP.x, anP.x, xnP.x)); eP.y = fexp2(fmaf(rrP.y, anP.y, xnP.y));
            nnP.x = fmaf(-2.0f, frcp(eP.x + 1.0f), 1.0f);
            nnP.y = fmaf(-2.0f, frcp(eP.y + 1.0f), 1.0f);
            rrQ.x = frcp(1.0f + fexp2(arQ.x)); rrQ.y = frcp(1.0f + fexp2(arQ.y));
            zzQ.x = frcp(1.0f + fexp2(azQ.x)); zzQ.y = frcp(1.0f + fexp2(azQ.y));
            eQ.x = fexp2(fmaf(rrQ.x, anQ.x, xnQ.x)); eQ.y = fexp2(fmaf(rrQ.y, anQ.y, xnQ.y));
            nnQ.x = fmaf(-2.0f, frcp(eQ.x + 1.0f), 1.0f);
            nnQ.y = fmaf(-2.0f, frcp(eQ.y + 1.0f), 1.0f);

            hnp[j] = pk_fma(zzP, hp[j] - nnP, nnP);   // (1-z)*n + z*h
            hnq[j] = pk_fma(zzQ, hq[j] - nnQ, nnQ);
        }
#pragma unroll
        for (int j = 0; j < NH; ++j) { hp[j] = hnp[j]; hq[j] = hnq[j]; }
    }

    // Streaming epilogue: per output o, l1 partial -> quad butterfly allreduce ->
    // +bias -> SELU -> l2 accumulate. No a1[] array stays live.
    const float SC = 1.0507009873554805f;
    const float AL = 1.6732632423543772f;
    f32x2 o0P = (f32x2){s_l2b[0], s_l2b[0]};
    f32x2 o1P = (f32x2){s_l2b[1], s_l2b[1]};
    f32x2 o0Q = o0P, o1Q = o1P;
#pragma unroll
    for (int o = 0; o < 20; ++o) {
        const float* lw = &s_l1w[o][0] + d * 12;
        q2 c0 = LDQ(lw), c1 = LDQ(lw + 4), c2 = LDQ(lw + 8);
        f32x2 sP = pk_fma_bl_cl(hp[0], c0.lo, c2.hi);   // h0*w0 + 0 (pad)
        PDOT9(sP, hp, c0, c1, c2)
        f32x2 sQ = pk_fma_bl_cl(hq[0], c0.lo, c2.hi);
        PDOT9(sQ, hq, c0, c1, c2)
        // quad allreduce (dirs live in lanes 4k..4k+3)
        sP.x += __shfl_xor(sP.x, 1, 64); sP.x += __shfl_xor(sP.x, 2, 64);
        sP.y += __shfl_xor(sP.y, 1, 64); sP.y += __shfl_xor(sP.y, 2, 64);
        sQ.x += __shfl_xor(sQ.x, 1, 64); sQ.x += __shfl_xor(sQ.x, 2, 64);
        sQ.y += __shfl_xor(sQ.y, 1, 64); sQ.y += __shfl_xor(sQ.y, 2, 64);
        const float b = s_l1b[o];
        float s0 = sP.x + b, s1 = sP.y + b, s2 = sQ.x + b, s3 = sQ.y + b;
        s0 = (s0 > 0.0f) ? SC * s0 : SC * AL * (fexp(s0) - 1.0f);
        s1 = (s1 > 0.0f) ? SC * s1 : SC * AL * (fexp(s1) - 1.0f);
        s2 = (s2 > 0.0f) ? SC * s2 : SC * AL * (fexp(s2) - 1.0f);
        s3 = (s3 > 0.0f) ? SC * s3 : SC * AL * (fexp(s3) - 1.0f);
        f32x2 suP = (f32x2){s0, s1}, suQ = (f32x2){s2, s3};
        o0P = pk_fma(suP, s_l2w2[0][o], o0P);
        o1P = pk_fma(suP, s_l2w2[1][o], o1P);
        o0Q = pk_fma(suQ, s_l2w2[0][o], o0Q);
        o1Q = pk_fma(suQ, s_l2w2[1][o], o1Q);
    }
    o0P.x = fminf(1.0f, fmaxf(-1.0f, o0P.x)); o0P.y = fminf(1.0f, fmaxf(-1.0f, o0P.y));
    o1P.x = fminf(1.0f, fmaxf(-1.0f, o1P.x)); o1P.y = fminf(1.0f, fmaxf(-1.0f, o1P.y));
    o0Q.x = fminf(1.0f, fmaxf(-1.0f, o0Q.x)); o0Q.y = fminf(1.0f, fmaxf(-1.0f, o0Q.y));
    o1Q.x = fminf(1.0f, fmaxf(-1.0f, o1Q.x)); o1Q.y = fminf(1.0f, fmaxf(-1.0f, o1Q.y));

    if (d == 0) {
        if (v01) *reinterpret_cast<float4*>(out + base * 2) = make_float4(o0P.x, o1P.x, o0P.y, o1P.y);
        if (v23) *reinterpret_cast<float4*>(out + base * 2 + 4) = make_float4(o0Q.x, o1Q.x, o0Q.y, o1Q.y);
        if (!v01 || !v23) {   // tail (unused at B=2^21, kept for generality)
            if (r0 < Btot && !v01) reinterpret_cast<float2*>(out)[r0] = make_float2(o0P.x, o1P.x);
            if (r2 < Btot && !v23) reinterpret_cast<float2*>(out)[r2] = make_float2(o0Q.x, o1Q.x);
        }
    }
}

extern "C" void kernel_launch(void* const* d_in, const int* in_sizes, int n_in,
                              void* d_out, int out_size, void* d_ws, size_t ws_size,
                              hipStream_t stream) {
    const float* state = (const float*)d_in[0];
    const int B = in_sizes[0] / 10;
    const int grid = (B + 255) / 256;   // 256 rows per 256-thread block (4 rows per lane-quad)

    actor_kernel<<<grid, 256, 0, stream>>>(
        state,
        (const float*)d_in[1],  (const float*)d_in[2],  (const float*)d_in[3],  (const float*)d_in[4],
        (const float*)d_in[5],  (const float*)d_in[6],  (const float*)d_in[7],  (const float*)d_in[8],
        (const float*)d_in[9],  (const float*)d_in[10], (const float*)d_in[11], (const float*)d_in[12],
        (const float*)d_in[13], (const float*)d_in[14], (const float*)d_in[15], (const float*)d_in[16],
        (const float*)d_in[17], (const float*)d_in[18], (const float*)d_in[19], (const float*)d_in[20],
        (float*)d_out, B);
}